// Round 5
// baseline (3024.242 us; speedup 1.0000x reference)
//
#include <hip/hip_runtime.h>

typedef __bf16 bf16x8 __attribute__((ext_vector_type(8)));
typedef float f32x4 __attribute__((ext_vector_type(4)));
typedef unsigned int u32x4 __attribute__((ext_vector_type(4)));

union UQ { uint4 q; u32x4 p; bf16x8 v; unsigned long long d[2]; };

__device__ __forceinline__ unsigned short f2bf(float x){
  union { float f; unsigned u; } c; c.f = x;
  return (unsigned short)((c.u + 0x7fffu + ((c.u >> 16) & 1u)) >> 16);
}

// zero flags (16384 ints)
__global__ void zero_flags(int* __restrict__ p){
  p[blockIdx.x * 256 + threadIdx.x] = 0;
}

// Pack W (512x512 f32 row-major) into canonical MFMA fragment stream:
// dst[(ntile*16 + kt)*64 + lane] = 8 bf16 of W[ntile*16 + (lane&15)][kt*32 + (lane>>4)*8 + j]
__global__ void pack_kernel(const float* __restrict__ W, uint4* __restrict__ dst){
  int tid  = blockIdx.x * 512 + threadIdx.x;   // 0..32767
  int lane = tid & 63;
  int kt   = (tid >> 6) & 15;
  int ntl  = tid >> 10;
  int row  = ntl * 16 + (lane & 15);
  int k0   = kt * 32 + ((lane >> 4) << 3);
  const float* s = &W[row * 512 + k0];
  unsigned a0 = f2bf(s[0]) | ((unsigned)f2bf(s[1]) << 16);
  unsigned a1 = f2bf(s[2]) | ((unsigned)f2bf(s[3]) << 16);
  unsigned a2 = f2bf(s[4]) | ((unsigned)f2bf(s[5]) << 16);
  unsigned a3 = f2bf(s[6]) | ((unsigned)f2bf(s[7]) << 16);
  dst[tid] = (uint4){a0, a1, a2, a3};
}

// h0[b][n] = sum_o init[b][o] * Whi[n][o]; also bf16 copy for step-0 fragments
__global__ void h0_kernel(const float* __restrict__ init, const float* __restrict__ Whi,
                          float* __restrict__ h0, unsigned short* __restrict__ hb0){
  int b = blockIdx.x, n = threadIdx.x;  // 256 x 512
  __shared__ float ic[512];
  ic[n] = init[b * 512 + n];
  __syncthreads();
  const float4* wr = (const float4*)&Whi[n * 512];
  float s = 0.f;
  #pragma unroll 8
  for (int o = 0; o < 128; o++){
    float4 w = wr[o];
    s += w.x * ic[4*o] + w.y * ic[4*o+1] + w.z * ic[4*o+2] + w.w * ic[4*o+3];
  }
  h0[b * 512 + n] = s;
  hb0[b * 512 + n] = f2bf(s);
}

// Recurrence: 32 WGs = 16 batch-groups (m) x 2 col-halves (sl).
// WG(m,sl): batches [16m..16m+16), cols [256sl..256sl+256).
// Wave w holds its 32-col W_rec slice in VGPRs (u0+u1 = 128 regs), pinned
// opaque via asm so the compiler cannot rematerialize the loads.
// u order rotated: j=0..7 own-half kts, j=8..15 peer-half kts.
// Own half h: LDS (swizzled, double-buffered). Peer half: direct agent-scope
// atomic loads from LLC exchange buffer (round-3-proven coherence protocol:
// atomicExch sends + vmcnt ack + agent fetch_add flag; agent load poll).
__global__ __launch_bounds__(512, 2)
void rnn_kernel(const float* __restrict__ inputs, const float* __restrict__ W_in,
                const float* __restrict__ b_in, const float* __restrict__ b_rec,
                const uint4* __restrict__ wfrag, const float* __restrict__ h0,
                const unsigned short* __restrict__ hb0,
                unsigned short* __restrict__ xbuf, int* __restrict__ flags,
                float* __restrict__ hidden){
  const int bid = blockIdx.x;
  const int m = bid & 15, sl = bid >> 4;
  const int g16 = m << 4;
  const int tid = threadIdx.x, w = tid >> 6, lane = tid & 63;
  const int col = lane & 15, quad = lane >> 4;
  const int nbase = (sl << 8) + (w << 5);   // this wave's 32 cols
  const int own8  = sl << 3;                // first own kt
  const int pbase = (1 - sl) << 8;          // peer k base

  __shared__ unsigned short hbuf[2][16 * 256];  // own-half h, swizzled, dbuf
  __shared__ float xin_s[2][32];

  // ---- persistent weights, rotated: u*[j] holds kt=(own8+j)&15; pinned.
  UQ u0[16], u1[16];
  {
    const int nt0 = nbase >> 4;
    #pragma unroll
    for (int j = 0; j < 16; j++){
      int kt = (own8 + j) & 15;
      u0[j].q = wfrag[(nt0 * 16 + kt) * 64 + lane];
      u1[j].q = wfrag[((nt0 + 1) * 16 + kt) * 64 + lane];
    }
    #pragma unroll
    for (int j = 0; j < 16; j++){
      asm volatile("" : "+v"(u0[j].d[0]), "+v"(u0[j].d[1]));
      asm volatile("" : "+v"(u1[j].d[0]), "+v"(u1[j].d[1]));
    }
  }

  float win0[8], win1[8], bcv[8];
  #pragma unroll
  for (int i = 0; i < 2; i++)
    #pragma unroll
    for (int r = 0; r < 4; r++){
      int n = nbase + i * 16 + (quad << 2) + r;
      win0[i*4+r] = W_in[2*n];  win1[i*4+r] = W_in[2*n+1];
      bcv[i*4+r]  = b_in[n] + b_rec[n];
    }

  float h[8];
  #pragma unroll
  for (int i = 0; i < 2; i++){
    float4 h4 = *(const float4*)&h0[(g16 + col) * 512 + nbase + i * 16 + (quad << 2)];
    h[i*4+0] = h4.x; h[i*4+1] = h4.y; h[i*4+2] = h4.z; h[i*4+3] = h4.w;
  }

  { // prelude: own half of h0 (bf16) -> hbuf[0], swizzled
    int b = tid >> 5, n0 = (tid & 31) << 3;
    uint4 v = *(const uint4*)&hb0[(g16 + b) * 512 + (sl << 8) + n0];
    *(uint4*)&hbuf[0][(b << 8) + (n0 ^ ((b & 7) << 3))] = v;
  }
  if (tid < 32) xin_s[0][tid] = inputs[((g16 + (tid >> 1)) * 512 + 0) * 2 + (tid & 1)];
  __syncthreads();

  int* flg_my = flags + ((sl * 16 + m) << 9);
  int* flg_pr = flags + (((1 - sl) * 16 + m) << 9);
  unsigned long long* xm = (unsigned long long*)xbuf + ((size_t)m << 12); // [2][16][128]
  const int swc = (col & 7) << 3;

  for (int t = 0; t < 512; t++){
    const int ls = t & 1;        // LDS read slot; xm send slot
    const int ps = ls ^ 1;       // xm slot holding peer h_{t-1}

    // ---- poll + issue peer-half loads first (latency hidden under own MFMAs)
    UQ pa[8];
    if (t == 0){
      #pragma unroll
      for (int kk = 0; kk < 8; kk++)
        pa[kk].q = *(const uint4*)&hb0[(g16 + col) * 512 + pbase + (kk << 5) + (quad << 3)];
    } else {
      if (lane == 0)
        while (__hip_atomic_load(&flg_pr[t - 1], __ATOMIC_RELAXED,
                                 __HIP_MEMORY_SCOPE_AGENT) < 8) {}
      const unsigned long long* psrc =
          xm + ((size_t)ps << 11) + (col << 7) + (pbase >> 2) + (quad << 1);
      #pragma unroll
      for (int kk = 0; kk < 8; kk++){
        pa[kk].d[0] = __hip_atomic_load(psrc + (kk << 3),
                        __ATOMIC_RELAXED, __HIP_MEMORY_SCOPE_AGENT);
        pa[kk].d[1] = __hip_atomic_load(psrc + (kk << 3) + 1,
                        __ATOMIC_RELAXED, __HIP_MEMORY_SCOPE_AGENT);
      }
    }

    // ---- own-half A-frags (LDS) + MFMAs, streaming (overlaps peer loads)
    f32x4 acc0 = {0.f,0.f,0.f,0.f}, acc1 = {0.f,0.f,0.f,0.f};
    #pragma unroll
    for (int kk = 0; kk < 8; kk++){
      UQ a;
      a.q = *(const uint4*)&hbuf[ls][(col << 8) + ((((kk << 5) + (quad << 3))) ^ swc)];
      acc0 = __builtin_amdgcn_mfma_f32_16x16x32_bf16(u0[kk].v, a.v, acc0, 0, 0, 0);
      acc1 = __builtin_amdgcn_mfma_f32_16x16x32_bf16(u1[kk].v, a.v, acc1, 0, 0, 0);
    }
    // ---- peer-half MFMAs
    #pragma unroll
    for (int kk = 0; kk < 8; kk++){
      acc0 = __builtin_amdgcn_mfma_f32_16x16x32_bf16(u0[8+kk].v, pa[kk].v, acc0, 0, 0, 0);
      acc1 = __builtin_amdgcn_mfma_f32_16x16x32_bf16(u1[8+kk].v, pa[kk].v, acc1, 0, 0, 0);
    }

    // ---- epilogue: h = 0.9h + 0.1 tanh(z)
    const float x0 = xin_s[ls][2 * col], x1 = xin_s[ls][2 * col + 1];
    unsigned short us[8];
    #pragma unroll
    for (int i = 0; i < 2; i++)
      #pragma unroll
      for (int r = 0; r < 4; r++){
        float zz = (i ? acc1[r] : acc0[r])
                 + fmaf(x0, win0[i*4+r], fmaf(x1, win1[i*4+r], bcv[i*4+r]));
        float e  = __expf(2.0f * zz);
        float th = 1.0f - 2.0f / (e + 1.0f);
        h[i*4+r] = 0.9f * h[i*4+r] + 0.1f * th;
        us[i*4+r] = f2bf(h[i*4+r]);
      }
    unsigned long long own0 =
        (unsigned long long)us[0] | ((unsigned long long)us[1] << 16)
      | ((unsigned long long)us[2] << 32) | ((unsigned long long)us[3] << 48);
    unsigned long long own1 =
        (unsigned long long)us[4] | ((unsigned long long)us[5] << 16)
      | ((unsigned long long)us[6] << 32) | ((unsigned long long)us[7] << 48);

    // ---- send h_t (slot ls) immediately; ack + flag after overlap work
    if (t < 511){
      unsigned long long* xdst = xm + ((size_t)ls << 11) + (col << 7) + (nbase >> 2) + quad;
      unsigned long long o0 = __hip_atomic_exchange(xdst, own0,
                                __ATOMIC_RELAXED, __HIP_MEMORY_SCOPE_AGENT);
      unsigned long long o1 = __hip_atomic_exchange(xdst + 4, own1,
                                __ATOMIC_RELAXED, __HIP_MEMORY_SCOPE_AGENT);
      asm volatile("" :: "v"(o0), "v"(o1));   // keep returns alive (performed-at-LLC ack)
    }

    // ---- overlap: own-half h_t -> LDS slot ls^1, x prefetch
    #pragma unroll
    for (int i = 0; i < 2; i++){
      int nloc = (w << 5) + (i << 4) + (quad << 2);
      *(unsigned long long*)&hbuf[ls ^ 1][(col << 8) + (nloc ^ swc)] = (i ? own1 : own0);
    }
    if (tid < 32 && t < 511)
      xin_s[ls ^ 1][tid] = inputs[((g16 + (tid >> 1)) * 512 + (t + 1)) * 2 + (tid & 1)];

    if (t < 511){
      asm volatile("s_waitcnt vmcnt(0)" ::: "memory");  // this wave's exchs performed
      if (lane == 0)
        __hip_atomic_fetch_add(&flg_my[t], 1, __ATOMIC_RELAXED, __HIP_MEMORY_SCOPE_AGENT);
    }

    // ---- hidden output (fire-and-forget; drained by next step's vmcnt/barrier)
    #pragma unroll
    for (int i = 0; i < 2; i++)
      *(float4*)&hidden[((size_t)(g16 + col) * 512 + t) * 512 + nbase + i * 16 + (quad << 2)] =
          (float4){h[i*4+0], h[i*4+1], h[i*4+2], h[i*4+3]};

    __syncthreads();   // LDS slot + xin visible for next step
  }
}

// outputs = hidden @ W_out^T : 1024 WGs x 8 waves; WG tile 128M x 512N.
__global__ __launch_bounds__(512, 2)
void out_gemm(const float* __restrict__ hidden, const uint4* __restrict__ wofrag,
              float* __restrict__ outp){
  const int tid  = threadIdx.x;
  const int w    = tid >> 6;
  const int lane = tid & 63;
  const int col  = lane & 15;
  const int quad = lane >> 4;
  const int ms   = w >> 1;
  const int nh   = w & 1;
  const int m0   = blockIdx.x << 7;

  __shared__ unsigned short albf[128 * 32];  // swizzled bf16 A-tile

  f32x4 acc[2][16];
  #pragma unroll
  for (int mt = 0; mt < 2; mt++)
    #pragma unroll
    for (int nt = 0; nt < 16; nt++) acc[mt][nt] = (f32x4){0.f, 0.f, 0.f, 0.f};

  for (int kt = 0; kt < 16; kt++){
    #pragma unroll
    for (int i = 0; i < 2; i++){
      int r  = (tid >> 3) + (i << 6);
      int c4 = (tid & 7) << 2;
      float4 v = *(const float4*)&hidden[(m0 + r) * 512 + (kt << 5) + c4];
      unsigned lo = f2bf(v.x) | ((unsigned)f2bf(v.y) << 16);
      unsigned hi = f2bf(v.z) | ((unsigned)f2bf(v.w) << 16);
      int byteoff = (r << 6) + ((c4 << 1) ^ (((r >> 1) & 3) << 4));
      *(uint2*)((char*)albf + byteoff) = (uint2){lo, hi};
    }
    __syncthreads();

    bf16x8 af[2];
    #pragma unroll
    for (int mt = 0; mt < 2; mt++){
      int rl = (ms << 5) + (mt << 4) + col;
      int byteoff = (rl << 6) + ((quad << 4) ^ (((rl >> 1) & 3) << 4));
      af[mt] = *(const bf16x8*)((const char*)albf + byteoff);
    }

    #pragma unroll
    for (int nt = 0; nt < 16; nt++){
      UQ u; u.q = wofrag[((((nh << 4) + nt) << 4) + kt) * 64 + lane];
      acc[0][nt] = __builtin_amdgcn_mfma_f32_16x16x32_bf16(af[0], u.v, acc[0][nt], 0, 0, 0);
      acc[1][nt] = __builtin_amdgcn_mfma_f32_16x16x32_bf16(af[1], u.v, acc[1][nt], 0, 0, 0);
    }
    __syncthreads();
  }

  #pragma unroll
  for (int mt = 0; mt < 2; mt++)
    #pragma unroll
    for (int nt = 0; nt < 16; nt++)
      #pragma unroll
      for (int r = 0; r < 4; r++)
        outp[(m0 + (ms << 5) + (mt << 4) + (quad << 2) + r) * 512
             + (nh << 8) + (nt << 4) + col] = acc[mt][nt][r];
}

extern "C" void kernel_launch(void* const* d_in, const int* in_sizes, int n_in,
                              void* d_out, int out_size, void* d_ws, size_t ws_size,
                              hipStream_t stream){
  const float* inputs  = (const float*)d_in[0];  // (256,512,2)
  const float* initc   = (const float*)d_in[1];  // (256,512)
  const float* W_in    = (const float*)d_in[2];  // (512,2)
  const float* b_in    = (const float*)d_in[3];  // (512)
  const float* W_rec   = (const float*)d_in[4];  // (512,512)
  const float* b_rec   = (const float*)d_in[5];  // (512)
  const float* W_out   = (const float*)d_in[6];  // (512,512)
  const float* W_hi    = (const float*)d_in[7];  // (512,512)

  float* hidden  = (float*)d_out;                 // 256*512*512
  float* outputs = hidden + (size_t)67108864;     // second half

  char* ws = (char*)d_ws;
  uint4*          wrec_f = (uint4*)ws;                           // 512 KB
  uint4*          wout_f = (uint4*)(ws + (512 << 10));           // 512 KB
  float*          h0     = (float*)(ws + (1024 << 10));          // 512 KB
  unsigned short* hb0    = (unsigned short*)(ws + (1536 << 10)); // 256 KB
  unsigned short* xbuf   = (unsigned short*)(ws + (1792 << 10)); // 512 KB (16 x 2slots x 16x512)
  int*            flags  = (int*)(ws + (2304 << 10));            // 64 KB (2 x 16 x 512)

  zero_flags<<<64, 256, 0, stream>>>(flags);
  pack_kernel<<<64, 512, 0, stream>>>(W_rec, wrec_f);
  pack_kernel<<<64, 512, 0, stream>>>(W_out, wout_f);
  h0_kernel<<<256, 512, 0, stream>>>(initc, W_hi, h0, hb0);
  rnn_kernel<<<32, 512, 0, stream>>>(inputs, W_in, b_in, b_rec, wrec_f, h0, hb0,
                                     xbuf, flags, hidden);
  out_gemm<<<1024, 512, 0, stream>>>(hidden, wout_f, outputs);
}

// Round 8
// 1718.880 us; speedup vs baseline: 1.7594x; 1.7594x over previous
//
#include <hip/hip_runtime.h>

typedef __bf16 bf16x8 __attribute__((ext_vector_type(8)));
typedef float f32x4 __attribute__((ext_vector_type(4)));
typedef unsigned int u32x4 __attribute__((ext_vector_type(4)));

union UQ { uint4 q; u32x4 p; bf16x8 v; __bf16 b[8]; unsigned long long d[2]; };

__device__ __forceinline__ unsigned short f2bf(float x){
  union { float f; unsigned u; } c; c.f = x;
  return (unsigned short)((c.u + 0x7fffu + ((c.u >> 16) & 1u)) >> 16);
}

// Pack W (512x512 f32 row-major) into canonical MFMA fragment stream:
// dst[(ntile*16 + kt)*64 + lane] = 8 bf16 of W[ntile*16 + (lane&15)][kt*32 + (lane>>4)*8 + j]
__global__ void pack_kernel(const float* __restrict__ W, uint4* __restrict__ dst){
  int tid  = blockIdx.x * 512 + threadIdx.x;   // 0..32767
  int lane = tid & 63;
  int kt   = (tid >> 6) & 15;
  int ntl  = tid >> 10;
  int row  = ntl * 16 + (lane & 15);
  int k0   = kt * 32 + ((lane >> 4) << 3);
  const float* s = &W[row * 512 + k0];
  unsigned a0 = f2bf(s[0]) | ((unsigned)f2bf(s[1]) << 16);
  unsigned a1 = f2bf(s[2]) | ((unsigned)f2bf(s[3]) << 16);
  unsigned a2 = f2bf(s[4]) | ((unsigned)f2bf(s[5]) << 16);
  unsigned a3 = f2bf(s[6]) | ((unsigned)f2bf(s[7]) << 16);
  dst[tid] = (uint4){a0, a1, a2, a3};
}

// h0[b][n] = sum_o init[b][o] * Whi[n][o]; also bf16 copy for step-0 staging
__global__ void h0_kernel(const float* __restrict__ init, const float* __restrict__ Whi,
                          float* __restrict__ h0, unsigned short* __restrict__ hb0){
  int b = blockIdx.x, n = threadIdx.x;  // 256 x 512
  __shared__ float ic[512];
  ic[n] = init[b * 512 + n];
  __syncthreads();
  const float4* wr = (const float4*)&Whi[n * 512];
  float s = 0.f;
  #pragma unroll 8
  for (int o = 0; o < 128; o++){
    float4 w = wr[o];
    s += w.x * ic[4*o] + w.y * ic[4*o+1] + w.z * ic[4*o+2] + w.w * ic[4*o+3];
  }
  h0[b * 512 + n] = s;
  hb0[b * 512 + n] = f2bf(s);
}

// Recurrence "fortress": 16 WGs x 512 threads, one per CU, ZERO cross-WG traffic.
// Wave w owns 64 cols (4 n-tiles). W_rec tiered:
//   kt 0..7  -> registers (32 frags = 128 VGPR, asm-loaded + pinned)
//   kt 8..11 -> LDS (128 KB, lane-linear, conflict-free)
//   kt 12..15-> streamed from L2 each step (staggered 4-frag batches, 64 VGPR)
// h: SINGLE-buffered bf16 LDS broadcast (swizzled), TWO barriers per step
// (r1-proven discipline: reads -> barrier -> writes -> barrier).
// x-projection + biases folded into MFMA via augmented K-tile:
//   h_aug[b][512..514] = (x0,x1,1);  W_aug[n][512..514] = (w0,w1,b_in+b_rec).
__global__ __launch_bounds__(512, 2)
void rnn_kernel(const float* __restrict__ inputs, const float* __restrict__ W_in,
                const float* __restrict__ b_in, const float* __restrict__ b_rec,
                const uint4* __restrict__ wfrag, const float* __restrict__ h0,
                const unsigned short* __restrict__ hb0, float* __restrict__ hidden){
  const int m = blockIdx.x;
  const int g16 = m << 4;
  const int tid = threadIdx.x, w = tid >> 6, lane = tid & 63;
  const int col = lane & 15, quad = lane >> 4;
  const int nbase = w << 6;
  const int swc = (col & 7) << 3;

  __shared__ unsigned short hbuf[16 * 512];  // 16 KB, swizzled bf16 h, SINGLE buffer
  __shared__ uint4 wlds[8][16][64];          // 128 KB, W kt 8..11

  // ---- persistent register weights kt0..7 (asm load: cannot rematerialize)
  UQ u[32];
  #pragma unroll
  for (int kt = 0; kt < 8; kt++)
    #pragma unroll
    for (int nt = 0; nt < 4; nt++){
      const uint4* src = &wfrag[(((w << 2) + nt) * 16 + kt) * 64 + lane];
      asm volatile("global_load_dwordx4 %0, %1, off"
                   : "=v"(u[kt * 4 + nt].p) : "v"(src) : "memory");
    }
  asm volatile("s_waitcnt vmcnt(0)" ::: "memory");
  #pragma unroll
  for (int j = 0; j < 32; j++)
    asm volatile("" : "+v"(u[j].d[0]), "+v"(u[j].d[1]));

  // ---- LDS weights kt8..11 (wave-local region)
  #pragma unroll
  for (int kt = 8; kt < 12; kt++)
    #pragma unroll
    for (int nt = 0; nt < 4; nt++)
      wlds[w][(kt - 8) * 4 + nt][lane] = wfrag[(((w << 2) + nt) * 16 + kt) * 64 + lane];

  // ---- augmented W frag (A-operand): quad0 lanes hold (w0, w1, bias)
  UQ uaug[4];
  #pragma unroll
  for (int nt = 0; nt < 4; nt++){
    uaug[nt].d[0] = 0; uaug[nt].d[1] = 0;
    if (quad == 0){
      int n = nbase + nt * 16 + col;
      uaug[nt].b[0] = (__bf16)W_in[2 * n];
      uaug[nt].b[1] = (__bf16)W_in[2 * n + 1];
      uaug[nt].b[2] = (__bf16)(b_in[n] + b_rec[n]);
    }
  }

  // ---- h regs: lane owns batch=col, 16 cols (4 per n-tile)
  float h[16];
  #pragma unroll
  for (int nt = 0; nt < 4; nt++){
    float4 h4 = *(const float4*)&h0[(g16 + col) * 512 + nbase + nt * 16 + (quad << 2)];
    h[nt*4+0] = h4.x; h[nt*4+1] = h4.y; h[nt*4+2] = h4.z; h[nt*4+3] = h4.w;
  }

  { // hbuf from hb0 (full 16x512, swizzled)
    int b = tid >> 5, n0 = (tid & 31) << 4;
    const uint4* s4 = (const uint4*)&hb0[(g16 + b) * 512 + n0];
    uint4 v0 = s4[0], v1 = s4[1];
    int sw = (b & 7) << 3;
    *(uint4*)&hbuf[(b << 9) + (n0 ^ sw)]       = v0;
    *(uint4*)&hbuf[(b << 9) + ((n0 + 8) ^ sw)] = v1;
  }
  __syncthreads();

  unsigned long long wsp = (unsigned long long)wfrag;
  const float2* xsrc = (const float2*)&inputs[((size_t)(g16 + col)) << 10];

#define ISSUE(b4) { int kt_ = 12 + (b4);                                          \
    _Pragma("unroll")                                                             \
    for (int nt_ = 0; nt_ < 4; nt_++)                                             \
      sv[(b4)*4 + nt_].q = ws[(((w << 2) + nt_) * 16 + kt_) * 64 + lane]; }

  for (int t = 0; t < 512; t++){
    asm volatile("" : "+s"(wsp));             // re-opaque: forbid hoisting stream loads
    const uint4* ws = (const uint4*)wsp;

    // aug B frag: (x0, x1, 1) on quad0
    UQ baug; baug.d[0] = 0; baug.d[1] = 0;
    float2 xv = xsrc[t];
    if (quad == 0){
      baug.b[0] = (__bf16)xv.x; baug.b[1] = (__bf16)xv.y; baug.b[2] = (__bf16)1.0f;
    }

    f32x4 acc[4];
    #pragma unroll
    for (int nt = 0; nt < 4; nt++)
      acc[nt] = __builtin_amdgcn_mfma_f32_16x16x32_bf16(uaug[nt].v, baug.v,
                                                        (f32x4){0.f,0.f,0.f,0.f}, 0, 0, 0);

    UQ sv[16];
    ISSUE(0);
    // kt 0..7: register weights
    #pragma unroll
    for (int kt = 0; kt < 8; kt++){
      UQ bfr;
      bfr.q = *(const uint4*)&hbuf[(col << 9) + (((kt << 5) + (quad << 3)) ^ swc)];
      #pragma unroll
      for (int nt = 0; nt < 4; nt++)
        acc[nt] = __builtin_amdgcn_mfma_f32_16x16x32_bf16(u[kt*4+nt].v, bfr.v, acc[nt], 0, 0, 0);
      if (kt == 0) ISSUE(1);
      if (kt == 2) ISSUE(2);
      if (kt == 4) ISSUE(3);
    }
    // kt 8..11: LDS weights
    #pragma unroll
    for (int kt = 8; kt < 12; kt++){
      UQ bfr;
      bfr.q = *(const uint4*)&hbuf[(col << 9) + (((kt << 5) + (quad << 3)) ^ swc)];
      #pragma unroll
      for (int nt = 0; nt < 4; nt++){
        UQ a; a.q = wlds[w][(kt - 8) * 4 + nt][lane];
        acc[nt] = __builtin_amdgcn_mfma_f32_16x16x32_bf16(a.v, bfr.v, acc[nt], 0, 0, 0);
      }
    }
    // kt 12..15: streamed weights
    #pragma unroll
    for (int kt = 12; kt < 16; kt++){
      UQ bfr;
      bfr.q = *(const uint4*)&hbuf[(col << 9) + (((kt << 5) + (quad << 3)) ^ swc)];
      #pragma unroll
      for (int nt = 0; nt < 4; nt++)
        acc[nt] = __builtin_amdgcn_mfma_f32_16x16x32_bf16(sv[(kt-12)*4+nt].v, bfr.v, acc[nt], 0, 0, 0);
    }

    __syncthreads();   // barrier A: ALL waves' hbuf reads complete before any write

    // ---- epilogue: h = 0.9h + 0.1 - 0.2/(exp(2z)+1); write hbuf + hidden
    #pragma unroll
    for (int nt = 0; nt < 4; nt++){
      UQ hw; hw.d[0] = 0; hw.d[1] = 0;
      #pragma unroll
      for (int r = 0; r < 4; r++){
        float z  = acc[nt][r];
        float e  = __expf(2.0f * z);
        float rc = __builtin_amdgcn_rcpf(e + 1.0f);
        float hn = fmaf(0.9f, h[nt*4+r], 0.1f) - 0.2f * rc;
        h[nt*4+r] = hn;
        hw.b[r] = (__bf16)hn;
      }
      *(unsigned long long*)&hbuf[(col << 9) + ((nbase + (nt << 4) + (quad << 2)) ^ swc)] = hw.d[0];
      *(float4*)&hidden[((size_t)(g16 + col) * 512 + t) * 512 + nbase + (nt << 4) + (quad << 2)] =
          (float4){h[nt*4+0], h[nt*4+1], h[nt*4+2], h[nt*4+3]};
    }
    __syncthreads();   // barrier B: h_t visible before next step's reads
  }
#undef ISSUE
}

// outputs = hidden @ W_out^T : 1024 WGs x 8 waves; WG tile 128M x 512N.
__global__ __launch_bounds__(512, 2)
void out_gemm(const float* __restrict__ hidden, const uint4* __restrict__ wofrag,
              float* __restrict__ outp){
  const int tid  = threadIdx.x;
  const int w    = tid >> 6;
  const int lane = tid & 63;
  const int col  = lane & 15;
  const int quad = lane >> 4;
  const int ms   = w >> 1;
  const int nh   = w & 1;
  const int m0   = blockIdx.x << 7;

  __shared__ unsigned short albf[128 * 32];  // swizzled bf16 A-tile

  f32x4 acc[2][16];
  #pragma unroll
  for (int mt = 0; mt < 2; mt++)
    #pragma unroll
    for (int nt = 0; nt < 16; nt++) acc[mt][nt] = (f32x4){0.f, 0.f, 0.f, 0.f};

  for (int kt = 0; kt < 16; kt++){
    #pragma unroll
    for (int i = 0; i < 2; i++){
      int r  = (tid >> 3) + (i << 6);
      int c4 = (tid & 7) << 2;
      float4 v = *(const float4*)&hidden[(m0 + r) * 512 + (kt << 5) + c4];
      unsigned lo = f2bf(v.x) | ((unsigned)f2bf(v.y) << 16);
      unsigned hi = f2bf(v.z) | ((unsigned)f2bf(v.w) << 16);
      int byteoff = (r << 6) + ((c4 << 1) ^ (((r >> 1) & 3) << 4));
      *(uint2*)((char*)albf + byteoff) = (uint2){lo, hi};
    }
    __syncthreads();

    bf16x8 af[2];
    #pragma unroll
    for (int mt = 0; mt < 2; mt++){
      int rl = (ms << 5) + (mt << 4) + col;
      int byteoff = (rl << 6) + ((quad << 4) ^ (((rl >> 1) & 3) << 4));
      af[mt] = *(const bf16x8*)((const char*)albf + byteoff);
    }

    #pragma unroll
    for (int nt = 0; nt < 16; nt++){
      UQ u; u.q = wofrag[((((nh << 4) + nt) << 4) + kt) * 64 + lane];
      acc[0][nt] = __builtin_amdgcn_mfma_f32_16x16x32_bf16(af[0], u.v, acc[0][nt], 0, 0, 0);
      acc[1][nt] = __builtin_amdgcn_mfma_f32_16x16x32_bf16(af[1], u.v, acc[1][nt], 0, 0, 0);
    }
    __syncthreads();
  }

  #pragma unroll
  for (int mt = 0; mt < 2; mt++)
    #pragma unroll
    for (int nt = 0; nt < 16; nt++)
      #pragma unroll
      for (int r = 0; r < 4; r++)
        outp[(m0 + (ms << 5) + (mt << 4) + (quad << 2) + r) * 512
             + (nh << 8) + (nt << 4) + col] = acc[mt][nt][r];
}

extern "C" void kernel_launch(void* const* d_in, const int* in_sizes, int n_in,
                              void* d_out, int out_size, void* d_ws, size_t ws_size,
                              hipStream_t stream){
  const float* inputs  = (const float*)d_in[0];  // (256,512,2)
  const float* initc   = (const float*)d_in[1];  // (256,512)
  const float* W_in    = (const float*)d_in[2];  // (512,2)
  const float* b_in    = (const float*)d_in[3];  // (512)
  const float* W_rec   = (const float*)d_in[4];  // (512,512)
  const float* b_rec   = (const float*)d_in[5];  // (512)
  const float* W_out   = (const float*)d_in[6];  // (512,512)
  const float* W_hi    = (const float*)d_in[7];  // (512,512)

  float* hidden  = (float*)d_out;                 // 256*512*512
  float* outputs = hidden + (size_t)67108864;     // second half

  char* ws = (char*)d_ws;
  uint4*          wrec_f = (uint4*)ws;                           // 512 KB
  uint4*          wout_f = (uint4*)(ws + (512 << 10));           // 512 KB
  float*          h0     = (float*)(ws + (1024 << 10));          // 512 KB
  unsigned short* hb0    = (unsigned short*)(ws + (1536 << 10)); // 256 KB

  pack_kernel<<<64, 512, 0, stream>>>(W_rec, wrec_f);
  pack_kernel<<<64, 512, 0, stream>>>(W_out, wout_f);
  h0_kernel<<<256, 512, 0, stream>>>(initc, W_hi, h0, hb0);
  rnn_kernel<<<16, 512, 0, stream>>>(inputs, W_in, b_in, b_rec, wrec_f, h0, hb0, hidden);
  out_gemm<<<1024, 512, 0, stream>>>(hidden, wout_f, outputs);
}

// Round 10
// 1699.116 us; speedup vs baseline: 1.7799x; 1.0116x over previous
//
#include <hip/hip_runtime.h>

typedef __bf16 bf16x8 __attribute__((ext_vector_type(8)));
typedef float f32x4 __attribute__((ext_vector_type(4)));
typedef unsigned int u32x4 __attribute__((ext_vector_type(4)));

union UQ { uint4 q; u32x4 p; bf16x8 v; __bf16 b[8]; unsigned long long d[2]; };

__device__ __forceinline__ unsigned short f2bf(float x){
  union { float f; unsigned u; } c; c.f = x;
  return (unsigned short)((c.u + 0x7fffu + ((c.u >> 16) & 1u)) >> 16);
}

// Pack W (512x512 f32 row-major) into canonical MFMA fragment stream:
// dst[(ntile*16 + kt)*64 + lane] = 8 bf16 of W[ntile*16 + (lane&15)][kt*32 + (lane>>4)*8 + j]
__global__ void pack_kernel(const float* __restrict__ W, uint4* __restrict__ dst){
  int tid  = blockIdx.x * 512 + threadIdx.x;   // 0..32767
  int lane = tid & 63;
  int kt   = (tid >> 6) & 15;
  int ntl  = tid >> 10;
  int row  = ntl * 16 + (lane & 15);
  int k0   = kt * 32 + ((lane >> 4) << 3);
  const float* s = &W[row * 512 + k0];
  unsigned a0 = f2bf(s[0]) | ((unsigned)f2bf(s[1]) << 16);
  unsigned a1 = f2bf(s[2]) | ((unsigned)f2bf(s[3]) << 16);
  unsigned a2 = f2bf(s[4]) | ((unsigned)f2bf(s[5]) << 16);
  unsigned a3 = f2bf(s[6]) | ((unsigned)f2bf(s[7]) << 16);
  dst[tid] = (uint4){a0, a1, a2, a3};
}

// h0[b][n] = sum_o init[b][o] * Whi[n][o]; also bf16 copy for step-0 staging
__global__ void h0_kernel(const float* __restrict__ init, const float* __restrict__ Whi,
                          float* __restrict__ h0, unsigned short* __restrict__ hb0){
  int b = blockIdx.x, n = threadIdx.x;  // 256 x 512
  __shared__ float ic[512];
  ic[n] = init[b * 512 + n];
  __syncthreads();
  const float4* wr = (const float4*)&Whi[n * 512];
  float s = 0.f;
  #pragma unroll 8
  for (int o = 0; o < 128; o++){
    float4 w = wr[o];
    s += w.x * ic[4*o] + w.y * ic[4*o+1] + w.z * ic[4*o+2] + w.w * ic[4*o+3];
  }
  h0[b * 512 + n] = s;
  hb0[b * 512 + n] = f2bf(s);
}

// Recurrence "fortress" (r8-proven) + hoisted h-fragment reads.
// 16 WGs x 512 threads, one per CU, ZERO cross-WG traffic.
// Wave w owns 64 cols (4 n-tiles). W_rec tiered:
//   kt 0..7  -> registers (32 frags = 128 VGPR, asm-loaded + pinned)
//   kt 8..11 -> LDS (128 KB, wave-local)
//   kt 12..15-> streamed from L2 each step (staggered batches)
// h: SINGLE-buffered bf16 LDS broadcast (swizzled), TWO barriers per step.
// x-projection + biases folded into MFMA via augmented K-tile.
__global__ __launch_bounds__(512, 2)
void rnn_kernel(const float* __restrict__ inputs, const float* __restrict__ W_in,
                const float* __restrict__ b_in, const float* __restrict__ b_rec,
                const uint4* __restrict__ wfrag, const float* __restrict__ h0,
                const unsigned short* __restrict__ hb0, float* __restrict__ hidden){
  const int m = blockIdx.x;
  const int g16 = m << 4;
  const int tid = threadIdx.x, w = tid >> 6, lane = tid & 63;
  const int col = lane & 15, quad = lane >> 4;
  const int nbase = w << 6;
  const int swc = (col & 7) << 3;

  __shared__ unsigned short hbuf[16 * 512];  // 16 KB, swizzled bf16 h, SINGLE buffer
  __shared__ uint4 wlds[8][16][64];          // 128 KB, W kt 8..11

  // ---- persistent register weights kt0..7 (asm load: cannot rematerialize)
  UQ u[32];
  #pragma unroll
  for (int kt = 0; kt < 8; kt++)
    #pragma unroll
    for (int nt = 0; nt < 4; nt++){
      const uint4* src = &wfrag[(((w << 2) + nt) * 16 + kt) * 64 + lane];
      asm volatile("global_load_dwordx4 %0, %1, off"
                   : "=v"(u[kt * 4 + nt].p) : "v"(src) : "memory");
    }
  asm volatile("s_waitcnt vmcnt(0)" ::: "memory");
  #pragma unroll
  for (int j = 0; j < 32; j++)
    asm volatile("" : "+v"(u[j].d[0]), "+v"(u[j].d[1]));

  // ---- LDS weights kt8..11 (wave-local region)
  #pragma unroll
  for (int kt = 8; kt < 12; kt++)
    #pragma unroll
    for (int nt = 0; nt < 4; nt++)
      wlds[w][(kt - 8) * 4 + nt][lane] = wfrag[(((w << 2) + nt) * 16 + kt) * 64 + lane];

  // ---- augmented W frag (A-operand): quad0 lanes hold (w0, w1, bias)
  UQ uaug[4];
  #pragma unroll
  for (int nt = 0; nt < 4; nt++){
    uaug[nt].d[0] = 0; uaug[nt].d[1] = 0;
    if (quad == 0){
      int n = nbase + nt * 16 + col;
      uaug[nt].b[0] = (__bf16)W_in[2 * n];
      uaug[nt].b[1] = (__bf16)W_in[2 * n + 1];
      uaug[nt].b[2] = (__bf16)(b_in[n] + b_rec[n]);
    }
  }

  // ---- h regs: lane owns batch=col, 16 cols (4 per n-tile)
  float h[16];
  #pragma unroll
  for (int nt = 0; nt < 4; nt++){
    float4 h4 = *(const float4*)&h0[(g16 + col) * 512 + nbase + nt * 16 + (quad << 2)];
    h[nt*4+0] = h4.x; h[nt*4+1] = h4.y; h[nt*4+2] = h4.z; h[nt*4+3] = h4.w;
  }

  { // hbuf from hb0 (full 16x512, swizzled)
    int b = tid >> 5, n0 = (tid & 31) << 4;
    const uint4* s4 = (const uint4*)&hb0[(g16 + b) * 512 + n0];
    uint4 v0 = s4[0], v1 = s4[1];
    int sw = (b & 7) << 3;
    *(uint4*)&hbuf[(b << 9) + (n0 ^ sw)]       = v0;
    *(uint4*)&hbuf[(b << 9) + ((n0 + 8) ^ sw)] = v1;
  }
  __syncthreads();

  unsigned long long wsp = (unsigned long long)wfrag;
  const float2* xsrc = (const float2*)&inputs[((size_t)(g16 + col)) << 10];

#define ISSUE(b4) { const int kt_ = 12 + (b4);                                    \
    _Pragma("unroll")                                                             \
    for (int nt_ = 0; nt_ < 4; nt_++)                                             \
      sv[(b4)*4 + nt_].q = ws[(((w << 2) + nt_) * 16 + kt_) * 64 + lane]; }

#define HREAD(kt_) *(const uint4*)&hbuf[(col << 9) + ((((kt_) << 5) + (quad << 3)) ^ swc)]

  for (int t = 0; t < 512; t++){
    asm volatile("" : "+s"(wsp));             // re-opaque: forbid hoisting stream loads
    const uint4* ws = (const uint4*)wsp;

    // aug B frag: (x0, x1, 1) on quad0
    UQ baug; baug.d[0] = 0; baug.d[1] = 0;
    float2 xv = xsrc[t];
    if (quad == 0){
      baug.b[0] = (__bf16)xv.x; baug.b[1] = (__bf16)xv.y; baug.b[2] = (__bf16)1.0f;
    }

    f32x4 acc[4];
    #pragma unroll
    for (int nt = 0; nt < 4; nt++)
      acc[nt] = __builtin_amdgcn_mfma_f32_16x16x32_bf16(uaug[nt].v, baug.v,
                                                        (f32x4){0.f,0.f,0.f,0.f}, 0, 0, 0);

    UQ sv[16];
    ISSUE(0);

    // ---- hoisted h-fragment reads: issue ALL 16 ds_reads up front so the
    // lgkmcnt drain overlaps MFMA issue (r8 serialized read->use per kt).
    UQ bh[16];
    #pragma unroll
    for (int kt = 0; kt < 16; kt++)
      bh[kt].q = HREAD(kt);

    // kt 0..7: register weights
    #pragma unroll
    for (int kt = 0; kt < 8; kt++){
      #pragma unroll
      for (int nt = 0; nt < 4; nt++)
        acc[nt] = __builtin_amdgcn_mfma_f32_16x16x32_bf16(u[kt*4+nt].v, bh[kt].v, acc[nt], 0, 0, 0);
      if (kt == 0) ISSUE(1);
      if (kt == 2) ISSUE(2);
      if (kt == 4) ISSUE(3);
    }
    // kt 8..11: LDS weights
    #pragma unroll
    for (int kt = 8; kt < 12; kt++){
      #pragma unroll
      for (int nt = 0; nt < 4; nt++){
        UQ a; a.q = wlds[w][(kt - 8) * 4 + nt][lane];
        acc[nt] = __builtin_amdgcn_mfma_f32_16x16x32_bf16(a.v, bh[kt].v, acc[nt], 0, 0, 0);
      }
    }
    // kt 12..15: streamed weights
    #pragma unroll
    for (int kt = 12; kt < 16; kt++){
      #pragma unroll
      for (int nt = 0; nt < 4; nt++)
        acc[nt] = __builtin_amdgcn_mfma_f32_16x16x32_bf16(sv[(kt-12)*4+nt].v, bh[kt].v, acc[nt], 0, 0, 0);
    }

    __syncthreads();   // barrier A: ALL waves' hbuf reads complete before any write

    // ---- epilogue: h = 0.9h + 0.1 - 0.2/(exp(2z)+1); write hbuf + hidden
    #pragma unroll
    for (int nt = 0; nt < 4; nt++){
      UQ hw; hw.d[0] = 0; hw.d[1] = 0;
      #pragma unroll
      for (int r = 0; r < 4; r++){
        float z  = acc[nt][r];
        float e  = __expf(2.0f * z);
        float rc = __builtin_amdgcn_rcpf(e + 1.0f);
        float hn = fmaf(0.9f, h[nt*4+r], 0.1f) - 0.2f * rc;
        h[nt*4+r] = hn;
        hw.b[r] = (__bf16)hn;
      }
      *(unsigned long long*)&hbuf[(col << 9) + ((nbase + (nt << 4) + (quad << 2)) ^ swc)] = hw.d[0];
      *(float4*)&hidden[((size_t)(g16 + col) * 512 + t) * 512 + nbase + (nt << 4) + (quad << 2)] =
          (float4){h[nt*4+0], h[nt*4+1], h[nt*4+2], h[nt*4+3]};
    }
    __syncthreads();   // barrier B: h_t visible before next step's reads
  }
#undef ISSUE
#undef HREAD
}

// outputs = hidden @ W_out^T : 1024 WGs x 8 waves; WG tile 128M x 512N.
// W-fragments for the current kt are staged into LDS once per iteration
// (32 KB, shared by all 8 waves) instead of each wave streaming 32 KB from
// L2 -> cuts W_out L2 traffic 8x (2 GB -> 0.5 GB aggregate).
__global__ __launch_bounds__(512, 2)
void out_gemm(const float* __restrict__ hidden, const uint4* __restrict__ wofrag,
              float* __restrict__ outp){
  const int tid  = threadIdx.x;
  const int w    = tid >> 6;
  const int lane = tid & 63;
  const int col  = lane & 15;
  const int quad = lane >> 4;
  const int ms   = w >> 1;
  const int nh   = w & 1;
  const int m0   = blockIdx.x << 7;

  __shared__ unsigned short albf[128 * 32];  // 8 KB swizzled bf16 A-tile
  __shared__ uint4 wq[32][64];               // 32 KB W-frags for current kt

  f32x4 acc[2][16];
  #pragma unroll
  for (int mt = 0; mt < 2; mt++)
    #pragma unroll
    for (int nt = 0; nt < 16; nt++) acc[mt][nt] = (f32x4){0.f, 0.f, 0.f, 0.f};

  for (int kt = 0; kt < 16; kt++){
    // stage A-tile (128x32 f32 -> bf16 swizzled)
    #pragma unroll
    for (int i = 0; i < 2; i++){
      int r  = (tid >> 3) + (i << 6);
      int c4 = (tid & 7) << 2;
      float4 v = *(const float4*)&hidden[(m0 + r) * 512 + (kt << 5) + c4];
      unsigned lo = f2bf(v.x) | ((unsigned)f2bf(v.y) << 16);
      unsigned hi = f2bf(v.z) | ((unsigned)f2bf(v.w) << 16);
      int byteoff = (r << 6) + ((c4 << 1) ^ (((r >> 1) & 3) << 4));
      *(uint2*)((char*)albf + byteoff) = (uint2){lo, hi};
    }
    // stage W-frags for this kt: 32 frags x 64 lanes, 4 per thread
    #pragma unroll
    for (int j = 0; j < 4; j++){
      int idx = (j << 9) + tid;            // 0..2047
      wq[idx >> 6][idx & 63] = wofrag[(((idx >> 6) << 4) + kt) * 64 + (idx & 63)];
    }
    __syncthreads();

    bf16x8 af[2];
    #pragma unroll
    for (int mt = 0; mt < 2; mt++){
      int rl = (ms << 5) + (mt << 4) + col;
      int byteoff = (rl << 6) + ((quad << 4) ^ (((rl >> 1) & 3) << 4));
      af[mt] = *(const bf16x8*)((const char*)albf + byteoff);
    }

    #pragma unroll
    for (int nt = 0; nt < 16; nt++){
      UQ u; u.q = wq[(nh << 4) + nt][lane];
      acc[0][nt] = __builtin_amdgcn_mfma_f32_16x16x32_bf16(af[0], u.v, acc[0][nt], 0, 0, 0);
      acc[1][nt] = __builtin_amdgcn_mfma_f32_16x16x32_bf16(af[1], u.v, acc[1][nt], 0, 0, 0);
    }
    __syncthreads();
  }

  #pragma unroll
  for (int mt = 0; mt < 2; mt++)
    #pragma unroll
    for (int nt = 0; nt < 16; nt++)
      #pragma unroll
      for (int r = 0; r < 4; r++)
        outp[(m0 + (ms << 5) + (mt << 4) + (quad << 2) + r) * 512
             + (nh << 8) + (nt << 4) + col] = acc[mt][nt][r];
}

extern "C" void kernel_launch(void* const* d_in, const int* in_sizes, int n_in,
                              void* d_out, int out_size, void* d_ws, size_t ws_size,
                              hipStream_t stream){
  const float* inputs  = (const float*)d_in[0];  // (256,512,2)
  const float* initc   = (const float*)d_in[1];  // (256,512)
  const float* W_in    = (const float*)d_in[2];  // (512,2)
  const float* b_in    = (const float*)d_in[3];  // (512)
  const float* W_rec   = (const float*)d_in[4];  // (512,512)
  const float* b_rec   = (const float*)d_in[5];  // (512)
  const float* W_out   = (const float*)d_in[6];  // (512,512)
  const float* W_hi    = (const float*)d_in[7];  // (512,512)

  float* hidden  = (float*)d_out;                 // 256*512*512
  float* outputs = hidden + (size_t)67108864;     // second half

  char* ws = (char*)d_ws;
  uint4*          wrec_f = (uint4*)ws;                           // 512 KB
  uint4*          wout_f = (uint4*)(ws + (512 << 10));           // 512 KB
  float*          h0     = (float*)(ws + (1024 << 10));          // 512 KB
  unsigned short* hb0    = (unsigned short*)(ws + (1536 << 10)); // 256 KB

  pack_kernel<<<64, 512, 0, stream>>>(W_rec, wrec_f);
  pack_kernel<<<64, 512, 0, stream>>>(W_out, wout_f);
  h0_kernel<<<256, 512, 0, stream>>>(initc, W_hi, h0, hb0);
  rnn_kernel<<<16, 512, 0, stream>>>(inputs, W_in, b_in, b_rec, wrec_f, h0, hb0, hidden);
  out_gemm<<<1024, 512, 0, stream>>>(hidden, wout_f, outputs);
}